// Round 3
// baseline (411.277 us; speedup 1.0000x reference)
//
#include <hip/hip_runtime.h>

#define V 8192
#define TILE 1024                 // columns per LDS tile (12 KB of delta)
#define NTILES (V / TILE)         // 8
#define C4_PER_TILE (TILE / 4)    // 256 float4 per component
#define ITERS (C4_PER_TILE / 64)  // 4 float4-chunks per lane per tile

// ws layout (floats): [0]=kinetic raw sum, [1]=elastic sum, [16..16+3V)=delta SoA
__global__ __launch_bounds__(256) void prep_kernel(
    const float* __restrict__ next_pos, const float* __restrict__ pos,
    const float* __restrict__ vel, const float* __restrict__ ext,
    const float* __restrict__ dt_p, float* __restrict__ ws) {
  int i = blockIdx.x * blockDim.x + threadIdx.x;
  if (i < 2) ws[i] = 0.f;  // zero accumulators every call (ws is poisoned)
  if (i < V) {
    float dt = dt_p[0];
    float dt2 = dt * dt;
    float* dx = ws + 16;
    float* dy = dx + V;
    float* dz = dy + V;
    dx[i] = next_pos[3*i+0] - (pos[3*i+0] + vel[3*i+0]*dt + ext[3*i+0]*dt2);
    dy[i] = next_pos[3*i+1] - (pos[3*i+1] + vel[3*i+1]*dt + ext[3*i+1]*dt2);
    dz[i] = next_pos[3*i+2] - (pos[3*i+2] + vel[3*i+2]*dt + ext[3*i+2]*dt2);
  }
}

// kinetic raw sum: sum_{r,c} M[r,c] * (dx[r]dx[c] + dy[r]dy[c] + dz[r]dz[c])
// One wave per row (8192 waves, 2048 blocks). Delta staged in 12 KB LDS tiles
// (ds_read -> lgkmcnt, separate from M's vmcnt). Per tile, all 4 M float4
// loads are hoisted before the FMA group to keep 4 KB/wave of HBM reads in
// flight; 8 blocks/CU * 4 waves = 32 waves/CU of concurrency.
__global__ __launch_bounds__(256) void kinetic_kernel(
    const float* __restrict__ M, const float* __restrict__ dsoa,
    float* __restrict__ acc) {
  const float4* __restrict__ dx4 = (const float4*)dsoa;
  const float4* __restrict__ dy4 = (const float4*)(dsoa + V);
  const float4* __restrict__ dz4 = (const float4*)(dsoa + 2 * V);

  __shared__ float4 lx[C4_PER_TILE], ly[C4_PER_TILE], lz[C4_PER_TILE];
  __shared__ float wsum[4];

  const int t = threadIdx.x;
  const int lane = t & 63;
  const int wv = t >> 6;
  const int row = blockIdx.x * 4 + wv;  // one row of M per wave

  // row-uniform delta components (same-address broadcast loads)
  const float rx = ((const float*)dx4)[row];
  const float ry = ((const float*)dy4)[row];
  const float rz = ((const float*)dz4)[row];

  const float4* __restrict__ Mrow4 = (const float4*)(M + (size_t)row * V);

  float a = 0.f;
  for (int tl = 0; tl < NTILES; ++tl) {
    // stage delta tile: 256 threads x 1 float4 per component
    const int g = tl * C4_PER_TILE + t;
    lx[t] = dx4[g];
    ly[t] = dy4[g];
    lz[t] = dz4[g];
    __syncthreads();

    // hoist the tile's 4 M loads (independent, stay in flight together)
    float4 mv[ITERS];
#pragma unroll
    for (int j = 0; j < ITERS; ++j)
      mv[j] = Mrow4[tl * C4_PER_TILE + j * 64 + lane];

#pragma unroll
    for (int j = 0; j < ITERS; ++j) {
      const int c = j * 64 + lane;
      const float4 cx = lx[c];
      const float4 cy = ly[c];
      const float4 cz = lz[c];
      const float4 m = mv[j];
      a += m.x * (rx * cx.x + ry * cy.x + rz * cz.x);
      a += m.y * (rx * cx.y + ry * cy.y + rz * cz.y);
      a += m.z * (rx * cx.z + ry * cy.z + rz * cz.z);
      a += m.w * (rx * cx.w + ry * cy.w + rz * cz.w);
    }
    __syncthreads();  // before next stage overwrites the tile
  }

  // 64-lane wave reduction
#pragma unroll
  for (int off = 32; off; off >>= 1) a += __shfl_down(a, off, 64);

  if (lane == 0) wsum[wv] = a;
  __syncthreads();
  if (t == 0) atomicAdd(acc, wsum[0] + wsum[1] + wsum[2] + wsum[3]);
}

__global__ __launch_bounds__(256) void elastic_kernel(
    const float* __restrict__ next_pos, const int* __restrict__ elements,
    const float* __restrict__ poly, const float* __restrict__ measure,
    const float* __restrict__ lam, const float* __restrict__ mu,
    float* __restrict__ acc, int E) {
  int e = blockIdx.x * blockDim.x + threadIdx.x;
  float contrib = 0.f;
  if (e < E) {
    float F00 = 0.f, F01 = 0.f, F02 = 0.f;
    float F10 = 0.f, F11 = 0.f, F12 = 0.f;
    float F20 = 0.f, F21 = 0.f, F22 = 0.f;
#pragma unroll
    for (int f = 0; f < 4; ++f) {
      int vi = elements[e * 4 + f];
      const float* p = next_pos + 3 * (size_t)vi;
      float px = p[0], py = p[1], pz = p[2];
      const float* b = poly + (size_t)e * 16 + f * 4;
      float b0 = b[0], b1 = b[1], b2 = b[2];
      F00 += px * b0; F01 += px * b1; F02 += px * b2;
      F10 += py * b0; F11 += py * b1; F12 += py * b2;
      F20 += pz * b0; F21 += pz * b1; F22 += pz * b2;
    }
    float Ic = F00*F00 + F01*F01 + F02*F02 +
               F10*F10 + F11*F11 + F12*F12 +
               F20*F20 + F21*F21 + F22*F22;
    float J = F00 * (F11 * F22 - F12 * F21)
            - F01 * (F10 * F22 - F12 * F20)
            + F02 * (F10 * F21 - F11 * F20);
    float l = lam[e], m = mu[e];
    float alpha = 0.75f * m / l + 1.f;  // (1 - 1/(3+1))*mu/lam + 1
    float Icv = fmaxf(Ic + 1.f, 0.f);
    float d = J - alpha;
    float psi = 0.5f * m * (Ic - 3.f) + 0.5f * l * d * d
              - 0.5f * m * logf(Icv + 1e-30f);
    contrib = psi * measure[e * 4 + 3];
  }
#pragma unroll
  for (int off = 32; off; off >>= 1) contrib += __shfl_down(contrib, off, 64);
  __shared__ float w[4];
  int lane = threadIdx.x & 63, wv = threadIdx.x >> 6;
  if (lane == 0) w[wv] = contrib;
  __syncthreads();
  if (threadIdx.x == 0) atomicAdd(acc, w[0] + w[1] + w[2] + w[3]);
}

__global__ void finalize_kernel(const float* __restrict__ ws,
                                const float* __restrict__ dt_p,
                                float* __restrict__ out) {
  float dt = dt_p[0];
  float inv_h = 1.f / dt;
  float coeff = 0.5f * inv_h * inv_h;
  float kin = coeff * ws[0];
  float ela = ws[1];
  out[0] = kin + ela;
  out[1] = kin;
  out[2] = ela;
}

extern "C" void kernel_launch(void* const* d_in, const int* in_sizes, int n_in,
                              void* d_out, int out_size, void* d_ws, size_t ws_size,
                              hipStream_t stream) {
  const float* next_pos = (const float*)d_in[0];
  const float* pos      = (const float*)d_in[1];
  const float* vel      = (const float*)d_in[2];
  const float* ext      = (const float*)d_in[3];
  const float* M        = (const float*)d_in[4];
  const int*   elements = (const int*)d_in[5];
  const float* poly     = (const float*)d_in[6];
  const float* measure  = (const float*)d_in[7];
  const float* lam      = (const float*)d_in[8];
  const float* mu       = (const float*)d_in[9];
  const float* dt_p     = (const float*)d_in[10];
  float* out = (float*)d_out;
  float* ws  = (float*)d_ws;
  const int E = in_sizes[5] / 4;

  prep_kernel<<<(V + 255) / 256, 256, 0, stream>>>(next_pos, pos, vel, ext, dt_p, ws);
  kinetic_kernel<<<V / 4, 256, 0, stream>>>(M, ws + 16, ws);
  elastic_kernel<<<(E + 255) / 256, 256, 0, stream>>>(next_pos, elements, poly,
                                                      measure, lam, mu, ws + 1, E);
  finalize_kernel<<<1, 1, 0, stream>>>(ws, dt_p, out);
}